// Round 1
// baseline (363.253 us; speedup 1.0000x reference)
//
#include <hip/hip_runtime.h>
#include <math.h>

#define B_ 2
#define L_ 512
#define V_ 64
#define D_ 128
#define NC_ 8
#define SCALE 0.08838834764831845f  // 1/sqrt(128)

#define KV 2        // k's per block
#define IT 64       // i rows per tile
#define JT 32       // j per tile
#define THREADS 256

// ---------------- Kernel A: per-(b,cluster) member lists (deterministic) ----
__global__ __launch_bounds__(L_) void cluster_index_kernel(
    const int* __restrict__ label, int* __restrict__ counts, int* __restrict__ jlist) {
  int b = blockIdx.x;
  int tid = threadIdx.x;
  __shared__ int lab[L_];
  lab[tid] = label[b * L_ + tid];
  if (tid < NC_) counts[b * NC_ + tid] = 0;
  __syncthreads();
  int my = lab[tid];
  int rank = 0, cnt = 0;
  for (int j = 0; j < L_; ++j) {
    int e = (lab[j] == my) ? 1 : 0;
    cnt += e;
    if (j < tid) rank += e;
  }
  jlist[(b * NC_ + my) * L_ + rank] = tid;
  if (rank == 0) counts[b * NC_ + my] = cnt;
}

// ---------------- Kernel B: S[b,j,d] = sum_v key[b,j,v,d] -------------------
__global__ __launch_bounds__(256) void sumkey_kernel(
    const float* __restrict__ key, float* __restrict__ S) {
  int idx = blockIdx.x * 256 + threadIdx.x;  // over B_*L_*D_ = 131072
  int d = idx & (D_ - 1);
  int bj = idx >> 7;  // b*L + j
  const float* kp = key + (size_t)bj * V_ * D_ + d;
  float s = 0.f;
#pragma unroll 8
  for (int v = 0; v < V_; ++v) s += kp[v * D_];
  S[idx] = s;
}

// ---------------- Kernel C: clustered flash attention -----------------------
// block = (b, c, kc); value/q read exactly once across the grid since clusters
// partition positions. 2 threads per (i,k) row, each owns a 64-wide d-half.
__global__ __launch_bounds__(THREADS) void clustered_attn_kernel(
    const float* __restrict__ q, const float* __restrict__ value,
    const float* __restrict__ S, const int* __restrict__ counts,
    const int* __restrict__ jlist, float* __restrict__ out) {
  int bid = blockIdx.x;
  int kc = bid & 31;         // V_/KV = 32 chunks
  int c = (bid >> 5) & 7;
  int b = bid >> 8;
  int n = counts[b * NC_ + c];
  if (n == 0) return;  // uniform

  int tid = threadIdx.x;
  int h = tid & 1;       // d-half
  int r = tid >> 1;      // row id 0..127
  int kk = r & 1;        // which k of the pair
  int il = r >> 1;       // i index within tile 0..63
  int k = kc * KV + kk;

  __shared__ int jl[L_];                    // 2 KB
  __shared__ float S_t[JT][D_];             // 16 KB (broadcast reads, no pad)
  __shared__ float V_t[JT][KV][D_ + 4];     // ~33.8 KB (+4 pad breaks conflicts)

  for (int j = tid; j < n; j += THREADS) jl[j] = jlist[(b * NC_ + c) * L_ + j];
  __syncthreads();

  for (int it0 = 0; it0 < n; it0 += IT) {
    bool active = (it0 + il) < n;
    int i = active ? jl[it0 + il] : jl[0];
    const float* qrow = q + (size_t)((b * L_ + i) * V_ + k) * D_ + h * 64;

    float acc[64];
#pragma unroll
    for (int dd = 0; dd < 64; ++dd) acc[dd] = 0.f;
    float m = -INFINITY, l = 0.f;

    for (int jt0 = 0; jt0 < n; jt0 += JT) {
      int jn = min(JT, n - jt0);
      __syncthreads();
      // cooperative load S tile: JT*32 float4
      for (int idx = tid; idx < JT * (D_ / 4); idx += THREADS) {
        int jj = idx >> 5;
        int d4 = idx & 31;
        int j = jl[jt0 + min(jj, jn - 1)];
        float4 v4 = *(const float4*)(S + (size_t)(b * L_ + j) * D_ + d4 * 4);
        *((float4*)(&S_t[jj][0]) + d4) = v4;
      }
      // cooperative load V tile: JT*KV*32 float4
      for (int idx = tid; idx < JT * KV * (D_ / 4); idx += THREADS) {
        int jj = idx >> 6;
        int rem = idx & 63;
        int kk2 = rem >> 5;
        int d4 = rem & 31;
        int j = jl[jt0 + min(jj, jn - 1)];
        float4 v4 = *(const float4*)(value +
            (size_t)((b * L_ + j) * V_ + kc * KV + kk2) * D_ + d4 * 4);
        *((float4*)(&V_t[jj][kk2][0]) + d4) = v4;
      }
      __syncthreads();

      if (active) {
        float s[JT];
#pragma unroll
        for (int jj = 0; jj < JT; ++jj) s[jj] = 0.f;
        // partial dot over this thread's d-half; S_t reads are lane-uniform
#pragma unroll
        for (int dc = 0; dc < 64; dc += 4) {
          float4 qv = *(const float4*)(qrow + dc);
#pragma unroll
          for (int jj = 0; jj < JT; ++jj) {
            const float* Sp = &S_t[jj][h * 64 + dc];
            s[jj] += qv.x * Sp[0] + qv.y * Sp[1] + qv.z * Sp[2] + qv.w * Sp[3];
          }
        }
        // combine halves (partner tid^1 shares row & activity), scale, max
        float mnew = m;
#pragma unroll
        for (int jj = 0; jj < JT; ++jj) {
          float v = s[jj] + __shfl_xor(s[jj], 1);
          v *= SCALE;
          s[jj] = v;
          if (jj < jn) mnew = fmaxf(mnew, v);
        }
        if (mnew > m) {
          float f = __expf(m - mnew);
#pragma unroll
          for (int dd = 0; dd < 64; ++dd) acc[dd] *= f;
          l *= f;
          m = mnew;
        }
        float sum = 0.f;
#pragma unroll
        for (int jj = 0; jj < JT; ++jj) {
          float p = (jj < jn) ? __expf(s[jj] - m) : 0.f;
          s[jj] = p;
          sum += p;
        }
        l += sum;
        // PV accumulate
#pragma unroll
        for (int jj = 0; jj < JT; ++jj) {
          if (jj < jn) {
            float p = s[jj];
            const float* vp = &V_t[jj][kk][h * 64];
#pragma unroll
            for (int dd = 0; dd < 64; dd += 4) {
              float4 vv = *(const float4*)(vp + dd);
              acc[dd] += p * vv.x;
              acc[dd + 1] += p * vv.y;
              acc[dd + 2] += p * vv.z;
              acc[dd + 3] += p * vv.w;
            }
          }
        }
      }
    }

    if (active) {
      float inv = 1.0f / l;
      float* op = out + (size_t)((b * L_ + i) * V_ + k) * D_ + h * 64;
#pragma unroll
      for (int dd = 0; dd < 64; dd += 4) {
        float4 o;
        o.x = acc[dd] * inv;
        o.y = acc[dd + 1] * inv;
        o.z = acc[dd + 2] * inv;
        o.w = acc[dd + 3] * inv;
        *(float4*)(op + dd) = o;
      }
    }
  }
}

extern "C" void kernel_launch(void* const* d_in, const int* in_sizes, int n_in,
                              void* d_out, int out_size, void* d_ws, size_t ws_size,
                              hipStream_t stream) {
  const float* q = (const float*)d_in[0];
  const float* key = (const float*)d_in[1];
  const float* value = (const float*)d_in[2];
  const int* label = (const int*)d_in[3];
  float* out = (float*)d_out;

  int* counts = (int*)d_ws;                                   // 64 B
  int* jlist = (int*)((char*)d_ws + 256);                     // 32 KB
  float* S = (float*)((char*)d_ws + 256 + B_ * NC_ * L_ * sizeof(int));  // 512 KB

  cluster_index_kernel<<<B_, L_, 0, stream>>>(label, counts, jlist);
  sumkey_kernel<<<(B_ * L_ * D_) / 256, 256, 0, stream>>>(key, S);
  clustered_attn_kernel<<<B_ * NC_ * (V_ / KV), THREADS, 0, stream>>>(
      q, value, S, counts, jlist, out);
}

// Round 3
// 227.711 us; speedup vs baseline: 1.5952x; 1.5952x over previous
//
#include <hip/hip_runtime.h>
#include <math.h>

#define B_ 2
#define L_ 512
#define V_ 64
#define D_ 128
#define NC_ 8
#define SCALE 0.08838834764831845f  // 1/sqrt(128)

#define JT 16       // j per tile
#define IT 64       // i rows per block tile
#define THREADS 256
#define MAXIT (L_ / IT)   // 8 i-tiles max per (b,c,k)

// ---------------- Kernel A: per-(b,cluster) member lists (deterministic) ----
__global__ __launch_bounds__(L_) void cluster_index_kernel(
    const int* __restrict__ label, int* __restrict__ counts, int* __restrict__ jlist) {
  int b = blockIdx.x;
  int tid = threadIdx.x;
  __shared__ int lab[L_];
  lab[tid] = label[b * L_ + tid];
  if (tid < NC_) counts[b * NC_ + tid] = 0;
  __syncthreads();
  int my = lab[tid];
  int rank = 0, cnt = 0;
  for (int j = 0; j < L_; ++j) {
    int e = (lab[j] == my) ? 1 : 0;
    cnt += e;
    if (j < tid) rank += e;
  }
  jlist[(b * NC_ + my) * L_ + rank] = tid;
  if (rank == 0) counts[b * NC_ + my] = cnt;
}

// ---------------- Kernel B: S[b,j,d] = sum_v key[b,j,v,d] -------------------
__global__ __launch_bounds__(256) void sumkey_kernel(
    const float* __restrict__ key, float* __restrict__ S) {
  int idx = blockIdx.x * 256 + threadIdx.x;  // over B_*L_*D_ = 131072
  int d = idx & (D_ - 1);
  int bj = idx >> 7;  // b*L + j
  const float* kp = key + (size_t)bj * V_ * D_ + d;
  float s = 0.f;
#pragma unroll 8
  for (int v = 0; v < V_; ++v) s += kp[v * D_];
  S[idx] = s;
}

// ---------------- Kernel C: clustered flash attention -----------------------
// block = (b, c, k, itile). Early-exit if itile beyond this cluster's rows.
// 4 threads per i-row; thread dq owns interleaved float4 chunks {dq+4t},
// so every LDS b128 read hits 4 disjoint bank groups (broadcast x16) -> no
// conflicts. acc[32]/thread keeps VGPR ~100 for 4 waves/SIMD.
__global__ __launch_bounds__(THREADS, 4) void clustered_attn_kernel(
    const float* __restrict__ q, const float* __restrict__ value,
    const float* __restrict__ S, const int* __restrict__ counts,
    const int* __restrict__ jlist, float* __restrict__ out) {
  int bid = blockIdx.x;
  int k = bid & (V_ - 1);
  int c = (bid >> 6) & (NC_ - 1);
  int b = (bid >> 9) & (B_ - 1);
  int itile = bid >> 10;
  int n = counts[b * NC_ + c];
  int it0 = itile * IT;
  if (it0 >= n) return;  // uniform early-exit

  int tid = threadIdx.x;
  int dq = tid & 3;      // d-quarter (interleaved chunks)
  int il = tid >> 2;     // row lane 0..63

  __shared__ int jl[L_];           // 2 KB
  __shared__ float S_t[JT][D_];    // 8 KB
  __shared__ float V_t[JT][D_];    // 8 KB

  for (int j = tid; j < n; j += THREADS) jl[j] = jlist[(b * NC_ + c) * L_ + j];
  __syncthreads();

  bool active = (it0 + il) < n;
  int i = jl[active ? it0 + il : it0];

  const float* qrow = q + (size_t)((b * L_ + i) * V_ + k) * D_;
  float4 q4[8];
#pragma unroll
  for (int t = 0; t < 8; ++t)
    q4[t] = *(const float4*)(qrow + (dq + 4 * t) * 4);

  float4 acc4[8];
#pragma unroll
  for (int t = 0; t < 8; ++t) acc4[t] = make_float4(0.f, 0.f, 0.f, 0.f);
  float m = -INFINITY, l = 0.f;

  for (int jt0 = 0; jt0 < n; jt0 += JT) {
    int jn = min(JT, n - jt0);
    __syncthreads();
    // stage S and V tiles: JT rows x 32 float4 each; 512 float4 over 256 thr
#pragma unroll
    for (int rep = 0; rep < 2; ++rep) {
      int idx = tid + rep * THREADS;
      int jj = idx >> 5;
      int d4 = idx & 31;
      int j = jl[jt0 + min(jj, jn - 1)];
      size_t rowbase = (size_t)(b * L_ + j);
      ((float4*)&S_t[0][0])[idx] = *(const float4*)(S + rowbase * D_ + d4 * 4);
      ((float4*)&V_t[0][0])[idx] =
          *(const float4*)(value + (rowbase * V_ + k) * D_ + d4 * 4);
    }
    __syncthreads();

    if (active) {
      float s[JT];
#pragma unroll
      for (int jj = 0; jj < JT; ++jj) s[jj] = 0.f;
      // partial dots over this thread's 8 chunks
#pragma unroll
      for (int t = 0; t < 8; ++t) {
        float4 qv = q4[t];
#pragma unroll
        for (int jj = 0; jj < JT; ++jj) {
          float4 sv = *((const float4*)&S_t[jj][0] + (dq + 4 * t));
          s[jj] = fmaf(qv.x, sv.x,
                  fmaf(qv.y, sv.y, fmaf(qv.z, sv.z, fmaf(qv.w, sv.w, s[jj]))));
        }
      }
      // combine 4 partials (lanes differ in bits 0..1 = dq), scale, max
      float mnew = m;
#pragma unroll
      for (int jj = 0; jj < JT; ++jj) {
        float v = s[jj] + __shfl_xor(s[jj], 1);
        v += __shfl_xor(v, 2);
        v *= SCALE;
        s[jj] = v;
        if (jj < jn) mnew = fmaxf(mnew, v);
      }
      if (mnew > m) {
        float f = __expf(m - mnew);
#pragma unroll
        for (int t = 0; t < 8; ++t) {
          acc4[t].x *= f; acc4[t].y *= f; acc4[t].z *= f; acc4[t].w *= f;
        }
        l *= f;
        m = mnew;
      }
      float sum = 0.f;
#pragma unroll
      for (int jj = 0; jj < JT; ++jj) {
        float p = (jj < jn) ? __expf(s[jj] - m) : 0.f;
        s[jj] = p;
        sum += p;
      }
      l += sum;
      // PV accumulate over this thread's chunks
#pragma unroll
      for (int jj = 0; jj < JT; ++jj) {
        if (jj < jn) {
          float p = s[jj];
#pragma unroll
          for (int t = 0; t < 8; ++t) {
            float4 vv = *((const float4*)&V_t[jj][0] + (dq + 4 * t));
            acc4[t].x = fmaf(p, vv.x, acc4[t].x);
            acc4[t].y = fmaf(p, vv.y, acc4[t].y);
            acc4[t].z = fmaf(p, vv.z, acc4[t].z);
            acc4[t].w = fmaf(p, vv.w, acc4[t].w);
          }
        }
      }
    }
  }

  if (active) {
    float inv = 1.0f / l;
    float* op = out + (size_t)((b * L_ + i) * V_ + k) * D_;
#pragma unroll
    for (int t = 0; t < 8; ++t) {
      float4 o;
      o.x = acc4[t].x * inv;
      o.y = acc4[t].y * inv;
      o.z = acc4[t].z * inv;
      o.w = acc4[t].w * inv;
      *(float4*)(op + (dq + 4 * t) * 4) = o;
    }
  }
}

extern "C" void kernel_launch(void* const* d_in, const int* in_sizes, int n_in,
                              void* d_out, int out_size, void* d_ws, size_t ws_size,
                              hipStream_t stream) {
  const float* q = (const float*)d_in[0];
  const float* key = (const float*)d_in[1];
  const float* value = (const float*)d_in[2];
  const int* label = (const int*)d_in[3];
  float* out = (float*)d_out;

  int* counts = (int*)d_ws;                                   // 64 B
  int* jlist = (int*)((char*)d_ws + 256);                     // 32 KB
  float* S = (float*)((char*)d_ws + 256 + B_ * NC_ * L_ * sizeof(int));  // 512 KB

  cluster_index_kernel<<<B_, L_, 0, stream>>>(label, counts, jlist);
  sumkey_kernel<<<(B_ * L_ * D_) / 256, 256, 0, stream>>>(key, S);
  clustered_attn_kernel<<<B_ * NC_ * V_ * MAXIT, THREADS, 0, stream>>>(
      q, value, S, counts, jlist, out);
}